// Round 5
// baseline (2516.498 us; speedup 1.0000x reference)
//
#include <hip/hip_runtime.h>

#define D 1024
#define DT 0.1f

typedef __attribute__((ext_vector_type(8))) __bf16 bf16x8;
typedef __attribute__((ext_vector_type(4))) float floatx4;

__device__ __forceinline__ unsigned short f2bf(float f) {
  unsigned int u = __builtin_bit_cast(unsigned int, f);
  u = u + 0x7fffu + ((u >> 16) & 1u);           // RNE
  return (unsigned short)(u >> 16);
}
__device__ __forceinline__ float bf2f(unsigned short b) {
  return __builtin_bit_cast(float, ((unsigned int)b) << 16);
}

__device__ __forceinline__ void gload_lds16(const void* g, void* l) {
  __builtin_amdgcn_global_load_lds(
      (const __attribute__((address_space(1))) void*)g,
      (__attribute__((address_space(3))) void*)l, 16, 0, 0);
}

// tanh(x) = sign(x) * (1-e)/(1+e), e = exp(-2|x|)  — e in (0,1], no overflow.
__device__ __forceinline__ float fast_tanh(float x) {
  float ax = __builtin_fabsf(x);
  float e  = __expf(-2.0f * ax);
  float y  = (1.0f - e) * __builtin_amdgcn_rcpf(1.0f + e);
  return __builtin_copysignf(y, x);
}

// Split fp32 -> (hi, lo) bf16 pair; optionally copy the fp32 source (for traj[0]).
__global__ void __launch_bounds__(256) split_kernel(
    const float* __restrict__ src, float* __restrict__ copy_dst,
    unsigned short* __restrict__ hi, unsigned short* __restrict__ lo) {
  const int i = blockIdx.x * blockDim.x + threadIdx.x;   // one float4 / thread
  float4 v = ((const float4*)src)[i];
  if (copy_dst) ((float4*)copy_dst)[i] = v;
  ushort4 h, l;
  h.x = f2bf(v.x); l.x = f2bf(v.x - bf2f(h.x));
  h.y = f2bf(v.y); l.y = f2bf(v.y - bf2f(h.y));
  h.z = f2bf(v.z); l.z = f2bf(v.z - bf2f(h.z));
  h.w = f2bf(v.w); l.w = f2bf(v.w - bf2f(h.w));
  ((ushort4*)hi)[i] = h;
  ((ushort4*)lo)[i] = l;
}

// One Euler step: z = h @ W_k^T + b ; h' = h + DT*tanh(z)
// bf16x3 split precision: acc += Ah*Bh + Al*Bh + Ah*Bl.
// 256 blocks x 512 threads; 64x64 tile/block; 8 waves 4x2, wave = 16x32.
//
// R5: A OPERAND DIRECT FROM GLOBAL (registers), B via LDS.
// The 16x16x32 A-fragment (lane=row l&15, 16B at k-offset quad*8) is loadable
// straight from row-major global as one b128/lane: no staging, no swizzle.
// 2x A redundancy across wc-pair waves is absorbed by L1 (16KB chunk < 32KB).
// Removes 32KB LDS-reads + 16KB LDS-writes per chunk (128 -> 80 KB, -37%)
// and moves A onto the TA/L1 path, parallel to the LDS port.
// (R2: K-split null -> exchange ate the win; R3: barriers/depth null;
//  R4: 2 blocks/CU regressed via 1.5x staging. LDS total traffic remains
//  the largest per-chunk term -> cut it without touching wave geometry.)
//
// B quad-buffered (4 x 16 KB = 64 KB), single barrier per chunk
// (stage-after-barrier WAR), region-batched counted vmcnt: each region
// issues exactly 6 VMEM ops (4 A-loads + 2 B-stages) so vmcnt(6) retires
// exactly the 2-regions-old batch. A registers triple-phased pa[c%3],
// fully unrolled -> static indices (no scratch).
// XCD-aware 2D swizzle: per-XCD footprint A(1MB)+B(2MB) = 3MB < 4MB L2.
__global__ void __launch_bounds__(512) step_kernel(
    const unsigned short* __restrict__ Ah, const unsigned short* __restrict__ Al,
    const unsigned short* __restrict__ Bh, const unsigned short* __restrict__ Bl,
    const float* __restrict__ bias,
    const float* __restrict__ hprev, float* __restrict__ hnext,
    unsigned short* __restrict__ Nh, unsigned short* __restrict__ Nl,
    float* __restrict__ feat) {
  __shared__ unsigned short lds[4 * 8192];   // 64 KiB: 4 bufs of sBh|sBl
  char* ldsb = (char*)lds;

  const int tid  = threadIdx.x;
  const int lane = tid & 63;
  const int wave = tid >> 6;       // 0..7
  const int wr   = wave >> 1;      // 0..3
  const int wc   = wave & 1;       // 0..1

  // ---- XCD-aware block -> (row-tile, col-tile): XCD x owns rows [4*(x>>1),+4),
  // cols [8*(x&1),+8); its 32 blocks (j = bid>>3) fill that 4x8 region.
  const int xcd = blockIdx.x & 7;
  const int j8  = blockIdx.x >> 3;
  const int rt  = ((xcd >> 1) << 2) | (j8 >> 3);   // 0..15
  const int ct  = ((xcd & 1) << 3) | (j8 & 7);     // 0..15
  const int row0 = rt << 6;
  const int col0 = ct << 6;

  const int quad = lane >> 4;
  const int l15  = lane & 15;
  const int x7   = lane & 7;

  // ---- B staging: wave stages rows [8*wave, 8*wave+8) of the 64x64 B tile.
  // LDS row = 128 B = 8 groups of 16 B; storage group g holds source group
  // g^(row&7); staged row bases are multiples of 8 so row&7 == srow.
  const int srow = lane >> 3;
  const int sgrp = x7 ^ srow;
  const long boff = (long)(col0 + wave * 8 + srow) * D + sgrp * 8;
  const unsigned short* gBh = Bh + boff;
  const unsigned short* gBl = Bl + boff;
  const int sw = wave * 1024;      // wave-uniform LDS dest base offset

  // ---- A direct-load addressing: lane reads row (row0+Ra), 16 B at k-offset
  const int Ra = (wr << 4) | l15;
  const unsigned short* gA_h = Ah + (long)(row0 + Ra) * D + (quad << 3);
  const unsigned short* gA_l = Al + (long)(row0 + Ra) * D + (quad << 3);

  // ---- epilogue prefetch: hprev + bias into registers before the K-loop ----
  const int ecol = col0 + (wc << 5) + l15;
  const int erow = row0 + (wr << 4) + (quad << 2);
  float hp0[4], hp1[4];
#pragma unroll
  for (int r = 0; r < 4; ++r) {
    const long i0 = (long)(erow + r) * D + ecol;
    hp0[r] = hprev[i0];
    hp1[r] = hprev[i0 + 16];
  }
  const float b0 = bias[ecol];
  const float b1 = bias[ecol + 16];

  // ---- B fragment addressing ----
  const int Rb0 = (wc << 5) | l15;
  const int Rb1 = Rb0 + 16;

  floatx4 acc0 = {0.f, 0.f, 0.f, 0.f};
  floatx4 acc1 = {0.f, 0.f, 0.f, 0.f};

  // A register phases: pa[p][0]=ah(kc0) pa[p][1]=ah(kc1) pa[p][2]=al(kc0) pa[p][3]=al(kc1)
  bf16x8 pa[3][4];

  auto stageB = [&](int ck) {
    const int kk = ck << 6;
    const int bo = (ck & 3) << 14;
    gload_lds16(gBh + kk, ldsb + bo + 0    + sw);
    gload_lds16(gBl + kk, ldsb + bo + 8192 + sw);
  };
  auto loadA = [&](int ck) {
    const int k0 = ck << 6;
    bf16x8* d = pa[ck % 3];
    d[0] = *(const bf16x8*)(gA_h + k0);
    d[1] = *(const bf16x8*)(gA_h + k0 + 32);
    d[2] = *(const bf16x8*)(gA_l + k0);
    d[3] = *(const bf16x8*)(gA_l + k0 + 32);
  };

  // pre-loop: pin VMEM queue order with compiler memory fences:
  // [B0(2), B1(2)] [A0(4), A1(4)] [B2(2)]  -> 14 outstanding
  stageB(0); stageB(1);
  asm volatile("" ::: "memory");
  loadA(0); loadA(1);
  asm volatile("" ::: "memory");
  stageB(2);

#pragma unroll
  for (int c = 0; c < 16; ++c) {
    // retire everything except the youngest region (6 ops): guarantees
    // A(c) regs + B(c) LDS (own share) complete; keeps 1 region in flight.
    if (c < 15) asm volatile("s_waitcnt vmcnt(6)" ::: "memory");
    else        asm volatile("s_waitcnt vmcnt(0)" ::: "memory");
    asm volatile("s_barrier" ::: "memory");   // data-arrival + WAR barrier
    // region c: A(c+2) -> pa[(c+2)%3] (disjoint from pa[c%3] in use);
    // B(c+3) -> buffer (c+3)&3 == (c-1)&3 (reads finished before barrier)
    if (c <= 13) loadA(c + 2);
    if (c <= 12) stageB(c + 3);
    const char* base = ldsb + ((c & 3) << 14);
    const bf16x8* A = pa[c % 3];
#pragma unroll
    for (int kc = 0; kc < 2; ++kc) {
      const int gs = (((kc << 2) | quad) ^ x7) << 4;
      bf16x8 ah  = A[kc];
      bf16x8 al  = A[2 + kc];
      bf16x8 bh0 = *(const bf16x8*)(base + 0    + Rb0 * 128 + gs);
      bf16x8 bl0 = *(const bf16x8*)(base + 8192 + Rb0 * 128 + gs);
      bf16x8 bh1 = *(const bf16x8*)(base + 0    + Rb1 * 128 + gs);
      bf16x8 bl1 = *(const bf16x8*)(base + 8192 + Rb1 * 128 + gs);
      acc0 = __builtin_amdgcn_mfma_f32_16x16x32_bf16(ah, bh0, acc0, 0, 0, 0);
      acc1 = __builtin_amdgcn_mfma_f32_16x16x32_bf16(ah, bh1, acc1, 0, 0, 0);
      acc0 = __builtin_amdgcn_mfma_f32_16x16x32_bf16(al, bh0, acc0, 0, 0, 0);
      acc1 = __builtin_amdgcn_mfma_f32_16x16x32_bf16(al, bh1, acc1, 0, 0, 0);
      acc0 = __builtin_amdgcn_mfma_f32_16x16x32_bf16(ah, bl0, acc0, 0, 0, 0);
      acc1 = __builtin_amdgcn_mfma_f32_16x16x32_bf16(ah, bl1, acc1, 0, 0, 0);
    }
  }

  // ---- epilogue: bias + tanh + Euler update; fp32 traj + bf16 hi/lo state ----
  const bool wf = (feat != nullptr);
#pragma unroll
  for (int r = 0; r < 4; ++r) {
    const long i0 = (long)(erow + r) * D + ecol;
    {
      float f  = fast_tanh(acc0[r] + b0);
      float hn = hp0[r] + DT * f;
      hnext[i0] = hn;
      unsigned short hb = f2bf(hn);
      Nh[i0] = hb;
      Nl[i0] = f2bf(hn - bf2f(hb));
      if (wf) feat[i0] = hn;
    }
    {
      const long i1 = i0 + 16;
      float f  = fast_tanh(acc1[r] + b1);
      float hn = hp1[r] + DT * f;
      hnext[i1] = hn;
      unsigned short hb = f2bf(hn);
      Nh[i1] = hb;
      Nl[i1] = f2bf(hn - bf2f(hb));
      if (wf) feat[i1] = hn;
    }
  }
}

extern "C" void kernel_launch(void* const* d_in, const int* in_sizes, int n_in,
                              void* d_out, int out_size, void* d_ws, size_t ws_size,
                              hipStream_t stream) {
  const float* x = (const float*)d_in[0];
  const float* W = (const float*)d_in[1];
  const float* b = (const float*)d_in[2];
  float* out  = (float*)d_out;
  float* feat = out;                       // [1024,1024] final features
  float* traj = out + (size_t)D * D;       // [101,1024,1024]

  const size_t M = (size_t)D * D;          // 1M elements
  unsigned short* ws = (unsigned short*)d_ws;
  const int splitBlocks = (int)(M / 4 / 256);   // 1024

  const bool big = ws_size >= (size_t)48 * 1024 * 1024;

  if (big) {
    // layout: Whi[10*M] | Wlo[10*M] | h hi/lo double buffers [4*M]  = 48 MB
    unsigned short* wh_all = ws;
    unsigned short* wl_all = wh_all + 10 * M;
    unsigned short* hbuf   = wl_all + 10 * M;
    unsigned short* hh[2] = {hbuf, hbuf + 2 * M};
    unsigned short* hl[2] = {hbuf + M, hbuf + 3 * M};

    // convert all 10 W slabs up-front (one launch), and seed h state + traj[0]
    split_kernel<<<splitBlocks * 10, 256, 0, stream>>>(W, (float*)nullptr, wh_all, wl_all);
    split_kernel<<<splitBlocks, 256, 0, stream>>>(x, traj, hh[0], hl[0]);

    for (int n = 0; n < 100; ++n) {
      const int k = n / 10;
      step_kernel<<<256, 512, 0, stream>>>(
          hh[n & 1], hl[n & 1], wh_all + (size_t)k * M, wl_all + (size_t)k * M,
          b + (size_t)k * D,
          traj + (size_t)n * M, traj + (size_t)(n + 1) * M,
          hh[(n + 1) & 1], hl[(n + 1) & 1],
          (n == 99) ? feat : nullptr);
    }
  } else {
    // fallback: per-slab W conversion (12 MB ws)
    unsigned short* wh    = ws;
    unsigned short* wl    = wh + M;
    unsigned short* hbuf  = wl + M;
    unsigned short* hh[2] = {hbuf, hbuf + 2 * M};
    unsigned short* hl[2] = {hbuf + M, hbuf + 3 * M};

    split_kernel<<<splitBlocks, 256, 0, stream>>>(x, traj, hh[0], hl[0]);
    for (int k = 0; k < 10; ++k) {
      split_kernel<<<splitBlocks, 256, 0, stream>>>(W + k * M, (float*)nullptr, wh, wl);
      for (int s = 0; s < 10; ++s) {
        const int n = k * 10 + s;
        step_kernel<<<256, 512, 0, stream>>>(
            hh[n & 1], hl[n & 1], wh, wl, b + (size_t)k * D,
            traj + (size_t)n * M, traj + (size_t)(n + 1) * M,
            hh[(n + 1) & 1], hl[(n + 1) & 1],
            (n == 99) ? feat : nullptr);
      }
    }
  }
}